// Round 9
// baseline (17381.689 us; speedup 1.0000x reference)
//
#include <hip/hip_runtime.h>
#include <hip/hip_bf16.h>
#include <math.h>

// Problem constants
#define N_B    256   // batch
#define L_SEQ  512   // sequence length
#define HID    512   // hidden
#define EMB_D  256   // embedding dim

#define NGROUPS 16   // 16 batch rows per group, one 1024-thread wg per group

// Workspace: E_sw only (pre-gathered/split/swizzled emb in A-frag order)
#define ESW_SHORTS_PER_BLK 8192   // per (g,t): 2 planes x 8 kk x 64 lanes x 8 = 16 KB
#define ESW_BYTES  ((size_t)NGROUPS * L_SEQ * ESW_SHORTS_PER_BLK * 2)  // 134,217,728

typedef short v8s __attribute__((ext_vector_type(8)));   // 8 bf16 MFMA A/B frag
typedef float v4f __attribute__((ext_vector_type(4)));   // MFMA C/D frag

static __device__ __forceinline__ unsigned short bf_bits(__hip_bfloat16 h) {
    union { __hip_bfloat16 b; unsigned short u; } c; c.b = h; return c.u;
}
static __device__ __forceinline__ void split_hilo(float v, short& hi, short& lo) {
    const __hip_bfloat16 h = __float2bfloat16(v);
    hi = (short)bf_bits(h);
    lo = (short)bf_bits(__float2bfloat16(v - __bfloat162float(h)));
}
static __device__ __forceinline__ void cvt8_hilo(const float* __restrict__ p,
                                                 v8s& hi, v8s& lo) {
    #pragma unroll
    for (int i = 0; i < 8; ++i) { short h, l; split_hilo(p[i], h, l); hi[i] = h; lo[i] = l; }
}
// async global->LDS, 16 B per lane; LDS dest = wave-uniform base + lane*16
static __device__ __forceinline__ void gl_lds16(const short* g, short* l) {
    __builtin_amdgcn_global_load_lds(
        (const __attribute__((address_space(1))) unsigned int*)g,
        (__attribute__((address_space(3))) unsigned int*)l, 16, 0, 0);
}
// fast tanh: 1 - 2/(exp(2x)+1); v_exp_f32-based, ~1e-7 abs err
static __device__ __forceinline__ float tanh_fast(float x) {
    const float z = __expf(2.0f * x);
    return 1.0f - 2.0f / (z + 1.0f);
}

// ---------------------------------------------------------------------------
// Precompute E_sw (unchanged from R7, correctness-proven): per (g,t) the 16
// emb rows split hi/lo and laid out in MFMA A-frag order:
//   short off = plane*4096 + (kk*64 + lane)*8 + i,  lane = m + 16*q',
//   element = emb[X[g*16+m][t]][kk*32 + q'*8 + i]
// ---------------------------------------------------------------------------
__global__ __launch_bounds__(256) void esw_build(
    const int* __restrict__ X, const float* __restrict__ emb,
    short* __restrict__ Esw)
{
    const int bid = blockIdx.x;           // g*512 + t
    const int g = bid >> 9, t = bid & 511;
    short* base = Esw + (size_t)bid * ESW_SHORTS_PER_BLK;
    #pragma unroll
    for (int h = 0; h < 2; ++h) {
        const int f    = threadIdx.x + h * 256;   // frag id 0..511
        const int kk   = f >> 6, lane = f & 63;
        const int m    = lane & 15, qp = lane >> 4;
        const int idx  = X[(g * 16 + m) * L_SEQ + t];
        const float* src = emb + (size_t)idx * EMB_D + kk * 32 + qp * 8;
        v8s hi8, lo8;
        cvt8_hilo(src, hi8, lo8);
        short* d = base + (size_t)(kk * 64 + lane) * 8;
        *(v8s*)d          = hi8;
        *(v8s*)(d + 4096) = lo8;
    }
}

// ---------------------------------------------------------------------------
// Single-CU persistent RNN per group: 16 wgs x 1024 thr (16 waves). Wave v
// owns output cols [32v, 32v+32) with Whh/Wxh hi/lo bf16 B-frags in registers
// (~440 VGPRs, fits 512 cap at 4 waves/SIMD). h(t) lives in LDS (flat A-frag
// layout = R7's measured-0-conflict read pattern), parity double-buffered;
// epilogue scatters h(t+1) directly into the other parity. ONE __syncthreads
// per step — no inter-wg flags, no L3 round-trip (that was R5-R7's invariant
// ~6 us/step floor). E(t+1) prefetched via global_load_lds during step t.
// ---------------------------------------------------------------------------
__global__ __launch_bounds__(1024, 4) void rnn_scan3(
    const float* __restrict__ Whh,
    const float* __restrict__ Whh_b,
    const float* __restrict__ Wxh,
    const float* __restrict__ Wxh_b,
    const short* __restrict__ Esw,
    float* __restrict__ out)
{
    const int g    = blockIdx.x;          // group = 16 batch rows
    const int tid  = threadIdx.x;
    const int v    = tid >> 6;            // wave 0..15
    const int l    = tid & 63;
    const int lo16 = l & 15;
    const int q    = l >> 4;
    const int nbase = g * 16;

    // LDS (shorts): h [P][plane][8192] = 64 KB at 0; E [P][8192] = 32 KB at 32768.
    __shared__ short lds[49152];
    short* lds_h = lds;            // parity P at P*16384; lo plane at +8192
    short* lds_e = lds + 32768;    // parity P at P*8192;  lo plane at +4096

    // B-frags: Whh cols 32v..32v+31 as 2 tiles x 16 kk hi/lo (256 VGPRs),
    // Wxh same cols 2 x 8 kk hi/lo (128 VGPRs).
    v8s bhi[2][16], blo[2][16], xhi[2][8], xlo[2][8];
    float bias[2];
    int coltile[2];
    #pragma unroll
    for (int c = 0; c < 2; ++c) {
        const int col = v * 32 + c * 16 + lo16;
        coltile[c] = col;
        const float* wp = Whh + (long)col * HID + q * 8;
        #pragma unroll
        for (int kk = 0; kk < 16; ++kk) cvt8_hilo(wp + kk * 32, bhi[c][kk], blo[c][kk]);
        const float* xp = Wxh + (long)col * EMB_D + q * 8;
        #pragma unroll
        for (int kk = 0; kk < 8; ++kk) cvt8_hilo(xp + kk * 32, xhi[c][kk], xlo[c][kk]);
        bias[c] = Whh_b[col] + Wxh_b[col];
    }

    const short* esrc = Esw + (size_t)(g * 512) * ESW_SHORTS_PER_BLK;

    // init: h(0) = 0 (parity 0 planes), stage E(0) (parity 0)
    for (int i = tid; i < 8192; i += 1024) ((unsigned int*)lds_h)[i] = 0u;
    gl_lds16(esrc + v * 512 + l * 8, lds_e + v * 512);   // 16 waves x 1 KB
    __syncthreads();

    for (int t = 0; t < L_SEQ; ++t) {
        const int P = t & 1;
        short* lh  = lds_h + P * 16384;
        short* le  = lds_e + P * 8192;
        short* lhN = lds_h + (P ^ 1) * 16384;

        // (1) prefetch E(t+1) into parity P^1 (lands before next barrier)
        if (t + 1 < L_SEQ) {
            const short* eb = esrc + (size_t)(t + 1) * ESW_SHORTS_PER_BLK;
            gl_lds16(eb + v * 512 + l * 8, lds_e + (P ^ 1) * 8192 + v * 512);
        }

        // (2) MFMA: xp (K=256) + h (K=512), hi/lo chains, fp32 acc
        v4f am0 = {0,0,0,0}, ae0 = {0,0,0,0};   // tile 0 main/err
        v4f am1 = {0,0,0,0}, ae1 = {0,0,0,0};   // tile 1 main/err
        #pragma unroll
        for (int kk = 0; kk < 8; ++kk) {
            v8s ah = *(const v8s*)(le + (kk * 64 + l) * 8);
            v8s al = *(const v8s*)(le + 4096 + (kk * 64 + l) * 8);
            am0 = __builtin_amdgcn_mfma_f32_16x16x32_bf16(ah, xhi[0][kk], am0, 0, 0, 0);
            ae0 = __builtin_amdgcn_mfma_f32_16x16x32_bf16(ah, xlo[0][kk], ae0, 0, 0, 0);
            ae0 = __builtin_amdgcn_mfma_f32_16x16x32_bf16(al, xhi[0][kk], ae0, 0, 0, 0);
            am1 = __builtin_amdgcn_mfma_f32_16x16x32_bf16(ah, xhi[1][kk], am1, 0, 0, 0);
            ae1 = __builtin_amdgcn_mfma_f32_16x16x32_bf16(ah, xlo[1][kk], ae1, 0, 0, 0);
            ae1 = __builtin_amdgcn_mfma_f32_16x16x32_bf16(al, xhi[1][kk], ae1, 0, 0, 0);
        }
        #pragma unroll
        for (int kk = 0; kk < 16; ++kk) {
            v8s ah = *(const v8s*)(lh + (kk * 64 + l) * 8);
            v8s al = *(const v8s*)(lh + 8192 + (kk * 64 + l) * 8);
            am0 = __builtin_amdgcn_mfma_f32_16x16x32_bf16(ah, bhi[0][kk], am0, 0, 0, 0);
            ae0 = __builtin_amdgcn_mfma_f32_16x16x32_bf16(ah, blo[0][kk], ae0, 0, 0, 0);
            ae0 = __builtin_amdgcn_mfma_f32_16x16x32_bf16(al, bhi[0][kk], ae0, 0, 0, 0);
            am1 = __builtin_amdgcn_mfma_f32_16x16x32_bf16(ah, bhi[1][kk], am1, 0, 0, 0);
            ae1 = __builtin_amdgcn_mfma_f32_16x16x32_bf16(ah, blo[1][kk], ae1, 0, 0, 0);
            ae1 = __builtin_amdgcn_mfma_f32_16x16x32_bf16(al, bhi[1][kk], ae1, 0, 0, 0);
        }

        // (3) epilogue: tanh, split, scatter h(t+1) into parity P^1 A-frag slots
        //     col coords: kk_s = v, q2 = 2c + (lo16>>3), i_s = lo16&7
        #pragma unroll
        for (int c = 0; c < 2; ++c) {
            const v4f am = c ? am1 : am0;
            const v4f ae = c ? ae1 : ae0;
            const int q2  = c * 2 + (lo16 >> 3);
            const int i_s = lo16 & 7;
            #pragma unroll
            for (int r = 0; r < 4; ++r) {
                const int m = q * 4 + r;             // C/D: row=(lane>>4)*4+r
                const float pre = am[r] + ae[r] + bias[c];
                const float hv = tanh_fast(pre);
                if (t < L_SEQ - 1) {
                    short hi, lo; split_hilo(hv, hi, lo);
                    const int off = (v * 64 + m + 16 * q2) * 8 + i_s;
                    lhN[off]        = hi;
                    lhN[off + 8192] = lo;
                } else {
                    out[(long)(nbase + m) * HID + coltile[c]] = hv;
                }
            }
        }

        // (4) the step's only barrier (also drains the E prefetch vmcnt)
        __syncthreads();
    }
}

// ---------------------------------------------------------------------------
extern "C" void kernel_launch(void* const* d_in, const int* in_sizes, int n_in,
                              void* d_out, int out_size, void* d_ws, size_t ws_size,
                              hipStream_t stream) {
    const int*   X     = (const int*)d_in[0];
    const float* emb   = (const float*)d_in[1];
    const float* Whh   = (const float*)d_in[2];
    const float* Whh_b = (const float*)d_in[3];
    const float* Wxh   = (const float*)d_in[4];
    const float* Wxh_b = (const float*)d_in[5];

    short* Esw = (short*)d_ws;   // 134 MB; fully rewritten every call

    esw_build<<<dim3(NGROUPS * L_SEQ), dim3(256), 0, stream>>>(X, emb, Esw);
    rnn_scan3<<<dim3(NGROUPS), dim3(1024), 0, stream>>>(
        Whh, Whh_b, Wxh, Wxh_b, Esw, (float*)d_out);
}

// Round 10
// 1937.703 us; speedup vs baseline: 8.9703x; 8.9703x over previous
//
#include <hip/hip_runtime.h>
#include <hip/hip_bf16.h>
#include <math.h>

// Problem constants
#define N_B    256   // batch
#define L_SEQ  512   // sequence length
#define HID    512   // hidden
#define EMB_D  256   // embedding dim

// 16 groups x 16 batch rows; 8 wgs/group each owning 64 Whh cols (hi/lo bf16
// in registers; 1.5 MB total weight frags REQUIRES >=8 CUs — R9's single-CU
// attempt spilled: VGPR file is 512 KB/CU). Per-wave flags: 32/group.
#define NGROUPS 16
#define GWGS    8
#define NFLAGS  32
#define FLAG_STRIDE 4    // ints; 16 B per flag (8 lines per group poll)

// Workspace: E_sw (pre-gathered/split/swizzled emb in A-frag order) + exchange + flags
#define ESW_SHORTS_PER_BLK 8192   // per (g,t): 2 planes x 8 kk x 64 lanes x 8 = 16 KB
#define ESW_BYTES  ((size_t)NGROUPS * L_SEQ * ESW_SHORTS_PER_BLK * 2)  // 134,217,728
#define EX_UINTS_PER_SLOT (16 * HID)                                   // 8192 = 32 KB
#define EX_BYTES   ((size_t)2 * NGROUPS * EX_UINTS_PER_SLOT * 4)       // 1 MB
#define FLAG_BYTES ((size_t)NGROUPS * NFLAGS * FLAG_STRIDE * 4)

typedef short v8s __attribute__((ext_vector_type(8)));   // 8 bf16 MFMA A/B frag
typedef float v4f __attribute__((ext_vector_type(4)));   // MFMA C/D frag

static __device__ __forceinline__ unsigned short bf_bits(__hip_bfloat16 h) {
    union { __hip_bfloat16 b; unsigned short u; } c; c.b = h; return c.u;
}
static __device__ __forceinline__ void split_hilo(float v, short& hi, short& lo) {
    const __hip_bfloat16 h = __float2bfloat16(v);
    hi = (short)bf_bits(h);
    lo = (short)bf_bits(__float2bfloat16(v - __bfloat162float(h)));
}
static __device__ __forceinline__ void cvt8_hilo(const float* __restrict__ p,
                                                 v8s& hi, v8s& lo) {
    #pragma unroll
    for (int i = 0; i < 8; ++i) { short h, l; split_hilo(p[i], h, l); hi[i] = h; lo[i] = l; }
}
// async global->LDS, 16 B per lane; LDS dest = wave-uniform base + lane*16
static __device__ __forceinline__ void gl_lds16(const short* g, short* l) {
    __builtin_amdgcn_global_load_lds(
        (const __attribute__((address_space(1))) unsigned int*)g,
        (__attribute__((address_space(3))) unsigned int*)l, 16, 0, 0);
}
// fast tanh: 1 - 2/(exp(2x)+1); v_exp_f32-based, ~1e-7 abs err
static __device__ __forceinline__ float tanh_fast(float x) {
    const float z = __expf(2.0f * x);
    return 1.0f - 2.0f / (z + 1.0f);
}

// ---------------------------------------------------------------------------
// Precompute E_sw (unchanged, correctness-proven): per (g,t) the 16 emb rows
// split hi/lo, MFMA A-frag order:
//   short off = plane*4096 + (kk*64 + lane)*8 + i,  lane = m + 16*q',
//   element = emb[X[g*16+m][t]][kk*32 + q'*8 + i]
// ---------------------------------------------------------------------------
__global__ __launch_bounds__(256) void esw_build(
    const int* __restrict__ X, const float* __restrict__ emb,
    short* __restrict__ Esw)
{
    const int bid = blockIdx.x;           // g*512 + t
    const int g = bid >> 9, t = bid & 511;
    short* base = Esw + (size_t)bid * ESW_SHORTS_PER_BLK;
    #pragma unroll
    for (int h = 0; h < 2; ++h) {
        const int f    = threadIdx.x + h * 256;   // frag id 0..511
        const int kk   = f >> 6, lane = f & 63;
        const int m    = lane & 15, qp = lane >> 4;
        const int idx  = X[(g * 16 + m) * L_SEQ + t];
        const float* src = emb + (size_t)idx * EMB_D + kk * 32 + qp * 8;
        v8s hi8, lo8;
        cvt8_hilo(src, hi8, lo8);
        short* d = base + (size_t)(kk * 64 + lane) * 8;
        *(v8s*)d          = hi8;
        *(v8s*)(d + 4096) = lo8;
    }
}

// ---------------------------------------------------------------------------
// Persistent RNN scan, R7 skeleton + coalesced publish + wave0 polling +
// E-MFMA-under-h-load. 128 wgs = 16 groups x 8 members, 256 thr (4 waves).
// Exchange holds h(t) packed hi|lo<<16 in A-frag order (parity dbuf). The
// publish path transposes C-frags through LDS so each wave stores ONE
// contiguous 1 KB region (kk_s*512 + (w&1)*256 .. +256 uints) as 4 fully
// line-coalesced sc1 dword stores (R7 scattered 64 partial-line txns/wave).
// Only wave 0 polls flags (s_sleep backoff); barrier1 broadcasts.
// ---------------------------------------------------------------------------
__global__ __launch_bounds__(256, 1) void rnn_scan4(
    const float* __restrict__ Whh,
    const float* __restrict__ Whh_b,
    const float* __restrict__ Wxh,
    const float* __restrict__ Wxh_b,
    const short* __restrict__ Esw,
    unsigned int* __restrict__ ex,
    int* __restrict__ flags,
    float* __restrict__ out)
{
    const int bid  = blockIdx.x;
    const int g    = bid & 15;    // group (members share XCD via %8 heuristic)
    const int j    = bid >> 4;    // member 0..7
    const int tid  = threadIdx.x;
    const int w    = tid >> 6;
    const int l    = tid & 63;
    const int lo16 = l & 15;
    const int q    = l >> 4;
    const int cbase = j * 64 + w * 16;
    const int nbase = g * 16;

    // LDS: h dbuf 64 KB + E dbuf 32 KB + 4 KB transpose scratch = 100 KB
    __shared__ short ldsbuf[49152];
    __shared__ unsigned int tp[4][256];
    short* lds_h = ldsbuf;          // P*16384 + plane*8192 + (kk*64+l)*8 + i
    short* lds_e = ldsbuf + 32768;  // P*8192  + plane*4096 + (kk*64+l)*8 + i

    // Whh 64-col slice as hi/lo bf16 B-frags (~128 VGPRs)
    v8s bhi[16], blo[16];
    {
        const float* wp = Whh + (long)(cbase + lo16) * HID + q * 8;
        #pragma unroll
        for (int kk = 0; kk < 16; ++kk) cvt8_hilo(wp + kk * 32, bhi[kk], blo[kk]);
    }
    // Wxh 64-col slice (~64 VGPRs)
    v8s xhi[8], xlo[8];
    {
        const float* wp = Wxh + (long)(cbase + lo16) * EMB_D + q * 8;
        #pragma unroll
        for (int kk = 0; kk < 8; ++kk) cvt8_hilo(wp + kk * 32, xhi[kk], xlo[kk]);
    }
    const int hcol = cbase + lo16;
    const float bias = Whh_b[hcol] + Wxh_b[hcol];

    // wave's contiguous 1 KB publish region in the exchange slot (uints):
    // kk_s = hcol>>5 = 2j + (w>>1); region covers q2 = 2(w&1)..2(w&1)+1.
    const int region = (2 * j + (w >> 1)) * 512 + (w & 1) * 256;

    int* myflags = flags + g * NFLAGS * FLAG_STRIDE;
    int* flp = myflags + (l & 31) * FLAG_STRIDE;
    const int myflag = (j * 4 + w) * FLAG_STRIDE;

    unsigned int* ex0 = ex + (size_t)g * EX_UINTS_PER_SLOT;              // parity 0
    unsigned int* ex1 = ex + (size_t)(NGROUPS + g) * EX_UINTS_PER_SLOT;  // parity 1
    const short* esrc = Esw + (size_t)(g * 512) * ESW_SHORTS_PER_BLK;

    // preamble: stage E(0) into parity-0 E buffer (drained by t=0 barrier1)
    #pragma unroll
    for (int c = 0; c < 4; ++c)
        gl_lds16(esrc + (w * 4 + c) * 512 + l * 8, lds_e + (w * 4 + c) * 512);

    for (int t = 0; t < L_SEQ; ++t) {
        const int P = t & 1;
        short* lh = lds_h + P * 16384;
        short* le = lds_e + P * 8192;
        unsigned int* exsrc = P ? ex1 : ex0;
        unsigned int* exdst = P ? ex0 : ex1;

        // (0) prefetch E(t+1) into other parity (in flight across whole step;
        //     safe: all waves passed prev barrier2 => prev E MFMAs done)
        if (t + 1 < L_SEQ) {
            const short* eb = esrc + (size_t)(t + 1) * ESW_SHORTS_PER_BLK;
            short* leN = lds_e + (P ^ 1) * 8192;
            #pragma unroll
            for (int c = 0; c < 4; ++c)
                gl_lds16(eb + (w * 4 + c) * 512 + l * 8, leN + (w * 4 + c) * 512);
        }

        // (1) wave0-only spin (relaxed sc1, s_sleep backoff); others idle at barrier
        if (w == 0) {
            int ok;
            do {
                int fl = 0x7fffffff;
                if (l < 32) fl = __hip_atomic_load(flp, __ATOMIC_RELAXED,
                                                   __HIP_MEMORY_SCOPE_AGENT);
                ok = __all((l >= 32) | (fl >= t));
                if (!ok) __builtin_amdgcn_s_sleep(1);
            } while (!ok);
        }
        __syncthreads();   // barrier1: flags broadcast; E(t) staged

        // (2) issue h loads (coalesced: 64 consecutive u64 per instr)
        unsigned long long hv64[16];
        {
            const unsigned long long* hs = (const unsigned long long*)exsrc;
            #pragma unroll
            for (int s = 0; s < 16; ++s)
                hv64[s] = __hip_atomic_load(hs + s * 256 + tid, __ATOMIC_RELAXED,
                                            __HIP_MEMORY_SCOPE_AGENT);
        }

        // (3) E MFMAs run under the h-load latency (peer-independent)
        v4f acc0 = {0,0,0,0}, acc1 = {0,0,0,0}, acc2 = {0,0,0,0};
        #pragma unroll
        for (int kk = 0; kk < 8; ++kk) {
            v8s ah = *(const v8s*)(le + (kk * 64 + l) * 8);
            v8s al = *(const v8s*)(le + 4096 + (kk * 64 + l) * 8);
            acc0 = __builtin_amdgcn_mfma_f32_16x16x32_bf16(ah, xhi[kk], acc0, 0, 0, 0);
            acc1 = __builtin_amdgcn_mfma_f32_16x16x32_bf16(ah, xlo[kk], acc1, 0, 0, 0);
            acc2 = __builtin_amdgcn_mfma_f32_16x16x32_bf16(al, xhi[kk], acc2, 0, 0, 0);
        }

        // (4) unpack h -> LDS planes (lane stride 1 u32: conflict-free)
        {
            unsigned int* lh_hi = (unsigned int*)lh;
            unsigned int* lh_lo = lh_hi + 4096;
            #pragma unroll
            for (int s = 0; s < 16; ++s) {
                const int o = s * 256 + tid;
                const unsigned int w0 = (unsigned int)hv64[s];
                const unsigned int w1 = (unsigned int)(hv64[s] >> 32);
                lh_hi[o] = (w0 & 0xffffu) | (w1 << 16);
                lh_lo[o] = (w0 >> 16)     | (w1 & 0xffff0000u);
            }
        }
        __syncthreads();   // barrier2: h LDS ready

        // (5) h MFMAs (K=512)
        #pragma unroll
        for (int kk = 0; kk < 16; ++kk) {
            v8s ah = *(const v8s*)(lh + (kk * 64 + l) * 8);
            v8s al = *(const v8s*)(lh + 8192 + (kk * 64 + l) * 8);
            acc0 = __builtin_amdgcn_mfma_f32_16x16x32_bf16(ah, bhi[kk], acc0, 0, 0, 0);
            acc1 = __builtin_amdgcn_mfma_f32_16x16x32_bf16(ah, blo[kk], acc1, 0, 0, 0);
            acc2 = __builtin_amdgcn_mfma_f32_16x16x32_bf16(al, bhi[kk], acc2, 0, 0, 0);
        }

        // (6) epilogue
        if (t < L_SEQ - 1) {
            // transpose to frag order in per-wave LDS scratch (intra-wave only;
            // DS pipe is in-order per wave, asm fence stops compiler reorder)
            unsigned int* myt = tp[w];
            #pragma unroll
            for (int r = 0; r < 4; ++r) {
                const int m = q * 4 + r;             // C/D: row=(lane>>4)*4+r
                const float pre = acc0[r] + acc1[r] + acc2[r] + bias;
                const float hv = tanh_fast(pre);
                short hi, lo; split_hilo(hv, hi, lo);
                myt[(m + 16 * (lo16 >> 3)) * 8 + (lo16 & 7)] =
                    (unsigned int)(unsigned short)hi
                    | ((unsigned int)(unsigned short)lo << 16);
            }
            asm volatile("s_waitcnt lgkmcnt(0)" ::: "memory");
            // 4 fully coalesced sc1 stores: 64 consecutive dwords each
            #pragma unroll
            for (int k = 0; k < 4; ++k) {
                const unsigned int val = myt[k * 64 + l];
                __hip_atomic_store(exdst + region + k * 64 + l, val,
                                   __ATOMIC_RELAXED, __HIP_MEMORY_SCOPE_AGENT);
            }
            asm volatile("s_waitcnt vmcnt(0)" ::: "memory");  // drain to L3
            if (l == 0)
                __hip_atomic_store(myflags + myflag, t + 1,
                                   __ATOMIC_RELAXED, __HIP_MEMORY_SCOPE_AGENT);
        } else {
            #pragma unroll
            for (int r = 0; r < 4; ++r) {
                const int m = q * 4 + r;
                const float pre = acc0[r] + acc1[r] + acc2[r] + bias;
                out[(long)(nbase + m) * HID + hcol] = tanh_fast(pre);
            }
        }
    }
}

// ---------------------------------------------------------------------------
extern "C" void kernel_launch(void* const* d_in, const int* in_sizes, int n_in,
                              void* d_out, int out_size, void* d_ws, size_t ws_size,
                              hipStream_t stream) {
    const int*   X     = (const int*)d_in[0];
    const float* emb   = (const float*)d_in[1];
    const float* Whh   = (const float*)d_in[2];
    const float* Whh_b = (const float*)d_in[3];
    const float* Wxh   = (const float*)d_in[4];
    const float* Wxh_b = (const float*)d_in[5];

    char* ws = (char*)d_ws;
    short*        Esw   = (short*)ws;
    unsigned int* ex    = (unsigned int*)(ws + ESW_BYTES);
    int*          flags = (int*)(ws + ESW_BYTES + EX_BYTES);

    // ws re-poisoned to 0xAA each timed launch: zero exchange (h(0)=0) + flags.
    hipMemsetAsync(ex, 0, EX_BYTES + FLAG_BYTES, stream);

    esw_build<<<dim3(NGROUPS * L_SEQ), dim3(256), 0, stream>>>(X, emb, Esw);
    rnn_scan4<<<dim3(NGROUPS * GWGS), dim3(256), 0, stream>>>(
        Whh, Whh_b, Wxh, Wxh_b, Esw, ex, flags, (float*)d_out);
}

// Round 11
// 1505.407 us; speedup vs baseline: 11.5462x; 1.2872x over previous
//
#include <hip/hip_runtime.h>
#include <hip/hip_bf16.h>
#include <math.h>

// Problem constants
#define N_B    256   // batch
#define L_SEQ  512   // sequence length
#define HID    512   // hidden
#define EMB_D  256   // embedding dim

// 16 groups x 16 batch rows; 8 wgs/group each owning 64 Whh cols (hi/lo bf16
// frags in registers; 1.5 MB aggregate requires >=8 CUs/group).
#define NGROUPS 16
#define GWGS    8

// Workspace: E_sw + exchange (parity dbuf). NO FLAGS: exchange words are
// self-validating via an epoch tag in bit16 (lo-plane LSB).
#define ESW_SHORTS_PER_BLK 8192   // per (g,t): 2 planes x 8 kk x 64 lanes x 8 = 16 KB
#define ESW_BYTES  ((size_t)NGROUPS * L_SEQ * ESW_SHORTS_PER_BLK * 2)  // 134,217,728
#define EX_UINTS_PER_SLOT (16 * HID)                                   // 8192 = 32 KB
#define EX_BYTES   ((size_t)2 * NGROUPS * EX_UINTS_PER_SLOT * 4)       // 1 MB

typedef short v8s __attribute__((ext_vector_type(8)));   // 8 bf16 MFMA A/B frag
typedef float v4f __attribute__((ext_vector_type(4)));   // MFMA C/D frag

static __device__ __forceinline__ unsigned short bf_bits(__hip_bfloat16 h) {
    union { __hip_bfloat16 b; unsigned short u; } c; c.b = h; return c.u;
}
static __device__ __forceinline__ void split_hilo(float v, short& hi, short& lo) {
    const __hip_bfloat16 h = __float2bfloat16(v);
    hi = (short)bf_bits(h);
    lo = (short)bf_bits(__float2bfloat16(v - __bfloat162float(h)));
}
static __device__ __forceinline__ void cvt8_hilo(const float* __restrict__ p,
                                                 v8s& hi, v8s& lo) {
    #pragma unroll
    for (int i = 0; i < 8; ++i) { short h, l; split_hilo(p[i], h, l); hi[i] = h; lo[i] = l; }
}
// async global->LDS, 16 B per lane; LDS dest = wave-uniform base + lane*16
static __device__ __forceinline__ void gl_lds16(const short* g, short* l) {
    __builtin_amdgcn_global_load_lds(
        (const __attribute__((address_space(1))) unsigned int*)g,
        (__attribute__((address_space(3))) unsigned int*)l, 16, 0, 0);
}
// fast tanh: 1 - 2/(exp(2x)+1); v_exp_f32-based, ~1e-7 abs err
static __device__ __forceinline__ float tanh_fast(float x) {
    const float z = __expf(2.0f * x);
    return 1.0f - 2.0f / (z + 1.0f);
}

// ---------------------------------------------------------------------------
// Precompute E_sw (unchanged, correctness-proven): per (g,t) the 16 emb rows
// split hi/lo, MFMA A-frag order:
//   short off = plane*4096 + (kk*64 + lane)*8 + i,  lane = m + 16*q',
//   element = emb[X[g*16+m][t]][kk*32 + q'*8 + i]
// ---------------------------------------------------------------------------
__global__ __launch_bounds__(256) void esw_build(
    const int* __restrict__ X, const float* __restrict__ emb,
    short* __restrict__ Esw)
{
    const int bid = blockIdx.x;           // g*512 + t
    const int g = bid >> 9, t = bid & 511;
    short* base = Esw + (size_t)bid * ESW_SHORTS_PER_BLK;
    #pragma unroll
    for (int h = 0; h < 2; ++h) {
        const int f    = threadIdx.x + h * 256;   // frag id 0..511
        const int kk   = f >> 6, lane = f & 63;
        const int m    = lane & 15, qp = lane >> 4;
        const int idx  = X[(g * 16 + m) * L_SEQ + t];
        const float* src = emb + (size_t)idx * EMB_D + kk * 32 + qp * 8;
        v8s hi8, lo8;
        cvt8_hilo(src, hi8, lo8);
        short* d = base + (size_t)(kk * 64 + lane) * 8;
        *(v8s*)d          = hi8;
        *(v8s*)(d + 4096) = lo8;
    }
}

// ---------------------------------------------------------------------------
// Persistent RNN scan with SELF-VALIDATING exchange (no flags, no drains):
// every packed word carries an epoch tag in bit16 (lo-LSB): write tag
// ((t+1)>>1)&1, read tag (t>>1)&1. Parity-0 buffer zeroed (h0=0, tag 0
// matches t=0 instantly); parity-1 memset 0xFF (tag 1 blocks t=1 until real
// step-0 data lands). Consumer waves poll THEIR OWN 16 u64 data loads until
// all tags match -> the poll IS the transfer (1 L3 RTT vs R10's 3: ack-drain
// + flag + load). Producers fire 4 coalesced sc1 stores and move on.
// WAR-safe at distance 2: j's epilogue(t) happens after j's poll(t) success
// <= all members published (t-1) <= all members finished poll(t-1) reads.
// ONE barrier per step (its vmcnt(0) also drains the E(t+1) prefetch).
// ---------------------------------------------------------------------------
__global__ __launch_bounds__(256, 1) void rnn_scan5(
    const float* __restrict__ Whh,
    const float* __restrict__ Whh_b,
    const float* __restrict__ Wxh,
    const float* __restrict__ Wxh_b,
    const short* __restrict__ Esw,
    unsigned int* __restrict__ ex,
    float* __restrict__ out)
{
    const int bid  = blockIdx.x;
    const int g    = bid & 15;    // group (members share XCD via %8 heuristic)
    const int j    = bid >> 4;    // member 0..7
    const int tid  = threadIdx.x;
    const int w    = tid >> 6;
    const int l    = tid & 63;
    const int lo16 = l & 15;
    const int q    = l >> 4;
    const int cbase = j * 64 + w * 16;
    const int nbase = g * 16;

    // LDS: h dbuf 64 KB + E dbuf 32 KB + 4 KB transpose scratch = 100 KB
    __shared__ short ldsbuf[49152];
    __shared__ unsigned int tp[4][256];
    short* lds_h = ldsbuf;          // P*16384 + plane*8192 + (kk*64+l)*8 + i
    short* lds_e = ldsbuf + 32768;  // P*8192  + plane*4096 + (kk*64+l)*8 + i

    // Whh 64-col slice as hi/lo bf16 B-frags
    v8s bhi[16], blo[16];
    {
        const float* wp = Whh + (long)(cbase + lo16) * HID + q * 8;
        #pragma unroll
        for (int kk = 0; kk < 16; ++kk) cvt8_hilo(wp + kk * 32, bhi[kk], blo[kk]);
    }
    // Wxh 64-col slice
    v8s xhi[8], xlo[8];
    {
        const float* wp = Wxh + (long)(cbase + lo16) * EMB_D + q * 8;
        #pragma unroll
        for (int kk = 0; kk < 8; ++kk) cvt8_hilo(wp + kk * 32, xhi[kk], xlo[kk]);
    }
    const int hcol = cbase + lo16;
    const float bias = Whh_b[hcol] + Wxh_b[hcol];

    // wave's contiguous 1 KB publish region (uints): kk_s = 2j + (w>>1),
    // covering q2 = 2(w&1)..2(w&1)+1.
    const int region = (2 * j + (w >> 1)) * 512 + (w & 1) * 256;

    unsigned int* ex0 = ex + (size_t)g * EX_UINTS_PER_SLOT;              // parity 0
    unsigned int* ex1 = ex + (size_t)(NGROUPS + g) * EX_UINTS_PER_SLOT;  // parity 1
    const short* esrc = Esw + (size_t)(g * 512) * ESW_SHORTS_PER_BLK;

    // preamble: stage E(0) into parity-0 E buffer; barrier makes it visible
    #pragma unroll
    for (int c = 0; c < 4; ++c)
        gl_lds16(esrc + (w * 4 + c) * 512 + l * 8, lds_e + (w * 4 + c) * 512);
    __syncthreads();

    for (int t = 0; t < L_SEQ; ++t) {
        const int P = t & 1;
        short* lh = lds_h + P * 16384;
        short* le = lds_e + P * 8192;
        unsigned int* exsrc = P ? ex1 : ex0;
        unsigned int* exdst = P ? ex0 : ex1;

        // (0) prefetch E(t+1) into other parity (drained by this step's barrier)
        if (t + 1 < L_SEQ) {
            const short* eb = esrc + (size_t)(t + 1) * ESW_SHORTS_PER_BLK;
            short* leN = lds_e + (P ^ 1) * 8192;
            #pragma unroll
            for (int c = 0; c < 4; ++c)
                gl_lds16(eb + (w * 4 + c) * 512 + l * 8, leN + (w * 4 + c) * 512);
        }

        // (1) E MFMAs (peer-independent; run while peers' h data propagates)
        v4f acc0 = {0,0,0,0}, acc1 = {0,0,0,0}, acc2 = {0,0,0,0};
        #pragma unroll
        for (int kk = 0; kk < 8; ++kk) {
            v8s ah = *(const v8s*)(le + (kk * 64 + l) * 8);
            v8s al = *(const v8s*)(le + 4096 + (kk * 64 + l) * 8);
            acc0 = __builtin_amdgcn_mfma_f32_16x16x32_bf16(ah, xhi[kk], acc0, 0, 0, 0);
            acc1 = __builtin_amdgcn_mfma_f32_16x16x32_bf16(ah, xlo[kk], acc1, 0, 0, 0);
            acc2 = __builtin_amdgcn_mfma_f32_16x16x32_bf16(al, xhi[kk], acc2, 0, 0, 0);
        }

        // (2) tag-poll h: reload own 16 u64 until every word's bit16 == read
        //     tag. The poll IS the data transfer (no flags, no ack drains).
        unsigned long long hv64[16];
        {
            const unsigned long long* hs = (const unsigned long long*)exsrc;
            const unsigned long long tagmask = 0x0001000000010000ull;
            const unsigned long long want = ((t >> 1) & 1) ? tagmask : 0ull;
            for (;;) {
                #pragma unroll
                for (int s = 0; s < 16; ++s)
                    hv64[s] = __hip_atomic_load(hs + s * 256 + tid,
                                                __ATOMIC_RELAXED,
                                                __HIP_MEMORY_SCOPE_AGENT);
                unsigned long long bad = 0;
                #pragma unroll
                for (int s = 0; s < 16; ++s) bad |= (hv64[s] ^ want) & tagmask;
                if (__all(bad == 0)) break;
            }
        }

        // (3) unpack h -> LDS planes (lane stride 1 u32: conflict-free)
        {
            unsigned int* lh_hi = (unsigned int*)lh;
            unsigned int* lh_lo = lh_hi + 4096;
            #pragma unroll
            for (int s = 0; s < 16; ++s) {
                const int o = s * 256 + tid;
                const unsigned int w0 = (unsigned int)hv64[s];
                const unsigned int w1 = (unsigned int)(hv64[s] >> 32);
                lh_hi[o] = (w0 & 0xffffu) | (w1 << 16);
                lh_lo[o] = (w0 >> 16)     | (w1 & 0xffff0000u);
            }
        }
        __syncthreads();   // the step's ONLY barrier: h LDS + E(t+1) staged

        // (4) h MFMAs (K=512)
        #pragma unroll
        for (int kk = 0; kk < 16; ++kk) {
            v8s ah = *(const v8s*)(lh + (kk * 64 + l) * 8);
            v8s al = *(const v8s*)(lh + 8192 + (kk * 64 + l) * 8);
            acc0 = __builtin_amdgcn_mfma_f32_16x16x32_bf16(ah, bhi[kk], acc0, 0, 0, 0);
            acc1 = __builtin_amdgcn_mfma_f32_16x16x32_bf16(ah, blo[kk], acc1, 0, 0, 0);
            acc2 = __builtin_amdgcn_mfma_f32_16x16x32_bf16(al, bhi[kk], acc2, 0, 0, 0);
        }

        // (5) epilogue: tanh, split, embed write tag in bit16, transpose via
        //     LDS scratch, 4 fully coalesced sc1 stores. NO drain, NO flag.
        if (t < L_SEQ - 1) {
            const unsigned int wtag = (unsigned int)(((t + 1) >> 1) & 1) << 16;
            unsigned int* myt = tp[w];
            #pragma unroll
            for (int r = 0; r < 4; ++r) {
                const int m = q * 4 + r;             // C/D: row=(lane>>4)*4+r
                const float pre = acc0[r] + acc1[r] + acc2[r] + bias;
                const float hv = tanh_fast(pre);
                short hi, lo; split_hilo(hv, hi, lo);
                unsigned int word = (unsigned int)(unsigned short)hi
                                  | ((unsigned int)(unsigned short)lo << 16);
                word = (word & 0xFFFEFFFFu) | wtag;   // lo-LSB := epoch tag
                myt[(m + 16 * (lo16 >> 3)) * 8 + (lo16 & 7)] = word;
            }
            asm volatile("s_waitcnt lgkmcnt(0)" ::: "memory");
            #pragma unroll
            for (int k = 0; k < 4; ++k) {
                const unsigned int val = myt[k * 64 + l];
                __hip_atomic_store(exdst + region + k * 64 + l, val,
                                   __ATOMIC_RELAXED, __HIP_MEMORY_SCOPE_AGENT);
            }
        } else {
            #pragma unroll
            for (int r = 0; r < 4; ++r) {
                const int m = q * 4 + r;
                const float pre = acc0[r] + acc1[r] + acc2[r] + bias;
                out[(long)(nbase + m) * HID + hcol] = tanh_fast(pre);
            }
        }
    }
}

// ---------------------------------------------------------------------------
extern "C" void kernel_launch(void* const* d_in, const int* in_sizes, int n_in,
                              void* d_out, int out_size, void* d_ws, size_t ws_size,
                              hipStream_t stream) {
    const int*   X     = (const int*)d_in[0];
    const float* emb   = (const float*)d_in[1];
    const float* Whh   = (const float*)d_in[2];
    const float* Whh_b = (const float*)d_in[3];
    const float* Wxh   = (const float*)d_in[4];
    const float* Wxh_b = (const float*)d_in[5];

    char* ws = (char*)d_ws;
    short*        Esw = (short*)ws;
    unsigned int* ex  = (unsigned int*)(ws + ESW_BYTES);

    // parity 0 := 0x00 (h(0)=0, tag 0 matches t=0 immediately);
    // parity 1 := 0xFF (tag 1 blocks t=1 until step-0 data lands).
    hipMemsetAsync(ex, 0x00, EX_BYTES / 2, stream);
    hipMemsetAsync((char*)ex + EX_BYTES / 2, 0xFF, EX_BYTES / 2, stream);

    esw_build<<<dim3(NGROUPS * L_SEQ), dim3(256), 0, stream>>>(X, emb, Esw);
    rnn_scan5<<<dim3(NGROUPS * GWGS), dim3(256), 0, stream>>>(
        Whh, Whh_b, Wxh, Wxh_b, Esw, ex, (float*)d_out);
}